// Round 1
// baseline (2337.741 us; speedup 1.0000x reference)
//
#include <hip/hip_runtime.h>
#include <hip/hip_bf16.h>

typedef unsigned short u16;
typedef short s16x8 __attribute__((ext_vector_type(8)));
typedef float f32x4 __attribute__((ext_vector_type(4)));

__device__ __forceinline__ u16 f2bf(float f){
  unsigned x = __float_as_uint(f);
  unsigned r = (x + 0x7fffu + ((x >> 16) & 1u)) >> 16;  // RNE
  return (u16)r;
}
__device__ __forceinline__ float bf2f(u16 u){
  return __uint_as_float(((unsigned)u) << 16);
}

// ---------------------------------------------------------------------------
// Conv 3x3 projection (f32 VALU, exact). One WG per frame.
// x: [512][64][16][16] f32 -> dst (bf16) head-major [b*8+h][s][dk*256+p]
// ---------------------------------------------------------------------------
__global__ __launch_bounds__(256) void proj_conv(
    const float* __restrict__ x, const float* __restrict__ W,
    const float* __restrict__ bias, u16* __restrict__ dst)
{
  __shared__ u16 xpad[64][324];            // [ci][18*18] zero-padded, bf16
  const int tid = threadIdx.x;
  const int frame = blockIdx.x;
  for (int i = tid; i < 64*324; i += 256) ((u16*)xpad)[i] = 0;
  __syncthreads();
  const float* xf = x + (size_t)frame * 16384;
  for (int i = tid; i < 16384; i += 256){
    int ci = i >> 8, p = i & 255, py = p >> 4, px = p & 15;
    xpad[ci][(py+1)*18 + px + 1] = f2bf(xf[i]);
  }
  __syncthreads();
  const int p = tid, py = p >> 4, px = p & 15;
  float acc[64];
  #pragma unroll
  for (int co = 0; co < 64; ++co) acc[co] = bias[co];
  for (int ci = 0; ci < 64; ++ci){
    float xv[9];
    #pragma unroll
    for (int dy = 0; dy < 3; ++dy)
      #pragma unroll
      for (int dx = 0; dx < 3; ++dx)
        xv[dy*3+dx] = bf2f(xpad[ci][(py+dy)*18 + px + dx]);
    const float* wp = W + ci*9;            // W[co][ci][3][3]
    #pragma unroll
    for (int co = 0; co < 64; ++co){
      const float* wc = wp + co*576;       // lane-uniform -> s_load
      float s = acc[co];
      #pragma unroll
      for (int t = 0; t < 9; ++t) s = fmaf(wc[t], xv[t], s);
      acc[co] = s;
    }
  }
  const int b = frame >> 8, sq = frame & 255;
  #pragma unroll
  for (int co = 0; co < 64; ++co){
    int h = co >> 3, dk = co & 7;
    dst[((size_t)((b*8 + h)*256 + sq))*2048 + dk*256 + p] = f2bf(acc[co]);
  }
}

// ---------------------------------------------------------------------------
// V transpose: vh [bh][s][2048] -> vt [bh][d][256]  (so PV B-frags are
// contiguous ushort8 loads). 64x64 LDS tile per WG.
// ---------------------------------------------------------------------------
__global__ __launch_bounds__(256) void transpose_v(
    const u16* __restrict__ vh, u16* __restrict__ vt)
{
  __shared__ u16 tile[64][72];             // stride 144B: 16B-aligned rows, 2-way banks
  const int tid = threadIdx.x;
  const int dt = blockIdx.x, st = blockIdx.y, bh = blockIdx.z;
  {
    int r = tid >> 2, c4 = tid & 3;        // r: s-row, c4: 16-col chunk
    const u16* src = vh + ((size_t)(bh*256 + st*64 + r))*2048 + dt*64 + c4*16;
    uint4 v0 = *(const uint4*)src;
    uint4 v1 = *(const uint4*)(src + 8);
    *(uint4*)&tile[r][c4*16]     = v0;
    *(uint4*)&tile[r][c4*16 + 8] = v1;
  }
  __syncthreads();
  {
    int dr = tid >> 2, s4 = tid & 3;
    u16 tmp[16];
    #pragma unroll
    for (int i = 0; i < 16; ++i) tmp[i] = tile[s4*16 + i][dr];
    u16* dstp = vt + ((size_t)(bh*2048 + dt*64 + dr))*256 + st*64 + s4*16;
    *(uint4*)dstp       = *(uint4*)&tmp[0];
    *(uint4*)(dstp + 8) = *(uint4*)&tmp[8];
  }
}

// ---------------------------------------------------------------------------
// Attention: per (bh, 32-row q-tile). 4 waves, each owns 64 S-cols.
// S = Q K^T (MFMA), softmax f32 (deferred divide), O = P V (MFMA).
// Writes O directly in conv-frame layout obuf[frame][c][p] bf16.
// ---------------------------------------------------------------------------
__global__ __launch_bounds__(256) void attn_kernel(
    const u16* __restrict__ qh, const u16* __restrict__ kh,
    const u16* __restrict__ vt, u16* __restrict__ obuf)
{
  const float SCALE = 0.022097086912079608f;   // 1/sqrt(2048)
  __shared__ __align__(16) u16 P[32*256];      // XOR-swizzled bf16 probs
  __shared__ float redA[4][32];
  __shared__ float redB[4][32];
  const int tid = threadIdx.x;
  const int w = tid >> 6, lane = tid & 63, lr = lane & 15, lg = lane >> 4;
  const int q0 = blockIdx.x * 32, bh = blockIdx.y, b = bh >> 3, h = bh & 7;
  const u16* Q = qh + ((size_t)(bh*256 + q0))*2048;
  const u16* K = kh + ((size_t)(bh*256 + w*64))*2048;   // this wave's 64 cols
  const u16* V = vt + (size_t)bh * 2048 * 256;

  const f32x4 zero4 = {0.f, 0.f, 0.f, 0.f};
  f32x4 sacc[2][4];
  #pragma unroll
  for (int m = 0; m < 2; ++m)
    #pragma unroll
    for (int n = 0; n < 4; ++n) sacc[m][n] = zero4;

  // ---- S = Q K^T ----
  for (int dstep = 0; dstep < 64; ++dstep){
    const int doff = dstep*32 + lg*8;
    s16x8 a0 = *(const s16x8*)(Q + (size_t)lr*2048 + doff);
    s16x8 a1 = *(const s16x8*)(Q + (size_t)(lr+16)*2048 + doff);
    #pragma unroll
    for (int n = 0; n < 4; ++n){
      s16x8 bk = *(const s16x8*)(K + (size_t)(n*16 + lr)*2048 + doff);
      sacc[0][n] = __builtin_amdgcn_mfma_f32_16x16x32_bf16(a0, bk, sacc[0][n], 0,0,0);
      sacc[1][n] = __builtin_amdgcn_mfma_f32_16x16x32_bf16(a1, bk, sacc[1][n], 0,0,0);
    }
  }

  // ---- row max (16-lane shfl, then cross-wave via LDS) ----
  float mx[2][4];
  #pragma unroll
  for (int m = 0; m < 2; ++m)
    #pragma unroll
    for (int r = 0; r < 4; ++r){
      float vv = fmaxf(fmaxf(sacc[m][0][r], sacc[m][1][r]),
                       fmaxf(sacc[m][2][r], sacc[m][3][r]));
      #pragma unroll
      for (int off = 1; off < 16; off <<= 1) vv = fmaxf(vv, __shfl_xor(vv, off));
      mx[m][r] = vv;
    }
  if (lr == 0){
    #pragma unroll
    for (int m = 0; m < 2; ++m)
      #pragma unroll
      for (int r = 0; r < 4; ++r) redA[w][m*16 + lg*4 + r] = mx[m][r];
  }
  __syncthreads();
  #pragma unroll
  for (int m = 0; m < 2; ++m)
    #pragma unroll
    for (int r = 0; r < 4; ++r){
      int row = m*16 + lg*4 + r;
      mx[m][r] = fmaxf(fmaxf(redA[0][row], redA[1][row]),
                       fmaxf(redA[2][row], redA[3][row]));
    }

  // ---- P = exp((S-max)*SCALE), bf16 -> swizzled LDS; row sums ----
  float sm[2][4];
  #pragma unroll
  for (int m = 0; m < 2; ++m)
    #pragma unroll
    for (int r = 0; r < 4; ++r) sm[m][r] = 0.f;
  #pragma unroll
  for (int m = 0; m < 2; ++m)
    #pragma unroll
    for (int n = 0; n < 4; ++n)
      #pragma unroll
      for (int r = 0; r < 4; ++r){
        float pv = __expf((sacc[m][n][r] - mx[m][r]) * SCALE);
        sm[m][r] += pv;
        int row = m*16 + lg*4 + r;
        int col = (w << 6) + (n << 4) + lr;
        unsigned off = (((unsigned)row << 9) + ((unsigned)col << 1))
                       ^ (unsigned)((row & 7) << 4);
        *(u16*)((char*)P + off) = f2bf(pv);
      }
  #pragma unroll
  for (int m = 0; m < 2; ++m)
    #pragma unroll
    for (int r = 0; r < 4; ++r){
      float vv = sm[m][r];
      #pragma unroll
      for (int off = 1; off < 16; off <<= 1) vv += __shfl_xor(vv, off);
      sm[m][r] = vv;
    }
  if (lr == 0){
    #pragma unroll
    for (int m = 0; m < 2; ++m)
      #pragma unroll
      for (int r = 0; r < 4; ++r) redB[w][m*16 + lg*4 + r] = sm[m][r];
  }
  __syncthreads();                         // also fences all P writes
  float rs[2][4];
  #pragma unroll
  for (int m = 0; m < 2; ++m)
    #pragma unroll
    for (int r = 0; r < 4; ++r){
      int row = m*16 + lg*4 + r;
      rs[m][r] = 1.0f / (redB[0][row] + redB[1][row] + redB[2][row] + redB[3][row]);
    }

  // ---- O = P V ; each wave owns 512 d-cols, processed in 64-col chunks ----
  #pragma unroll 1
  for (int chunk = 0; chunk < 8; ++chunk){
    const int nb = w*512 + chunk*64;
    f32x4 oacc[2][4];
    #pragma unroll
    for (int m = 0; m < 2; ++m)
      #pragma unroll
      for (int n = 0; n < 4; ++n) oacc[m][n] = zero4;
    #pragma unroll
    for (int kt = 0; kt < 8; ++kt){
      unsigned koff = (unsigned)(kt*64 + lg*16);
      unsigned off0 = (((unsigned)lr << 9) + koff) ^ (unsigned)((lr & 7) << 4);
      unsigned off1 = (((unsigned)(lr+16) << 9) + koff) ^ (unsigned)(((lr+16) & 7) << 4);
      s16x8 a0 = *(const s16x8*)((const char*)P + off0);
      s16x8 a1 = *(const s16x8*)((const char*)P + off1);
      #pragma unroll
      for (int n = 0; n < 4; ++n){
        const u16* vp = V + (size_t)(nb + n*16 + lr)*256 + kt*32 + lg*8;
        s16x8 bv = *(const s16x8*)vp;
        oacc[0][n] = __builtin_amdgcn_mfma_f32_16x16x32_bf16(a0, bv, oacc[0][n], 0,0,0);
        oacc[1][n] = __builtin_amdgcn_mfma_f32_16x16x32_bf16(a1, bv, oacc[1][n], 0,0,0);
      }
    }
    #pragma unroll
    for (int m = 0; m < 2; ++m)
      #pragma unroll
      for (int n = 0; n < 4; ++n)
        #pragma unroll
        for (int r = 0; r < 4; ++r){
          float o = oacc[m][n][r] * rs[m][r];
          int qrow = q0 + m*16 + lg*4 + r;
          int d = nb + n*16 + lr;
          int frame = b*256 + qrow;
          int c = h*8 + (d >> 8);
          obuf[((size_t)(frame*64 + c))*256 + (d & 255)] = f2bf(o);
        }
  }
}

// ---------------------------------------------------------------------------
// Output conv (f32 VALU). Input obuf bf16 frames, output f32 d_out.
// ---------------------------------------------------------------------------
__global__ __launch_bounds__(256) void conv_out(
    const u16* __restrict__ xin, const float* __restrict__ W,
    const float* __restrict__ bias, float* __restrict__ out)
{
  __shared__ u16 xpad[64][324];
  const int tid = threadIdx.x;
  const int frame = blockIdx.x;
  for (int i = tid; i < 64*324; i += 256) ((u16*)xpad)[i] = 0;
  __syncthreads();
  const u16* xf = xin + (size_t)frame * 16384;
  for (int i = tid; i < 16384; i += 256){
    int ci = i >> 8, p = i & 255, py = p >> 4, px = p & 15;
    xpad[ci][(py+1)*18 + px + 1] = xf[i];
  }
  __syncthreads();
  const int p = tid, py = p >> 4, px = p & 15;
  float acc[64];
  #pragma unroll
  for (int co = 0; co < 64; ++co) acc[co] = bias[co];
  for (int ci = 0; ci < 64; ++ci){
    float xv[9];
    #pragma unroll
    for (int dy = 0; dy < 3; ++dy)
      #pragma unroll
      for (int dx = 0; dx < 3; ++dx)
        xv[dy*3+dx] = bf2f(xpad[ci][(py+dy)*18 + px + dx]);
    const float* wp = W + ci*9;
    #pragma unroll
    for (int co = 0; co < 64; ++co){
      const float* wc = wp + co*576;
      float s = acc[co];
      #pragma unroll
      for (int t = 0; t < 9; ++t) s = fmaf(wc[t], xv[t], s);
      acc[co] = s;
    }
  }
  #pragma unroll
  for (int co = 0; co < 64; ++co)
    out[(size_t)frame*16384 + co*256 + p] = acc[co];
}

// ---------------------------------------------------------------------------
extern "C" void kernel_launch(void* const* d_in, const int* in_sizes, int n_in,
                              void* d_out, int out_size, void* d_ws, size_t ws_size,
                              hipStream_t stream)
{
  const float* q  = (const float*)d_in[0];
  const float* k  = (const float*)d_in[1];
  const float* v  = (const float*)d_in[2];
  const float* Wq = (const float*)d_in[3];
  const float* bq = (const float*)d_in[4];
  const float* Wk = (const float*)d_in[5];
  const float* bk = (const float*)d_in[6];
  const float* Wv = (const float*)d_in[7];
  const float* bv = (const float*)d_in[8];
  const float* Wo = (const float*)d_in[9];
  const float* bo = (const float*)d_in[10];
  float* out = (float*)d_out;

  // Workspace layout (64 MB total):
  //   qh: [0,16MB)   kh: [16,32MB)   vh: [32,48MB)   vt: [48,64MB)
  //   obuf (attention output frames, bf16) reuses vh region (vh dead after
  //   transpose_v; attn reads only qh/kh/vt).
  char* ws = (char*)d_ws;
  u16* qh = (u16*)(ws);
  u16* kh = (u16*)(ws + (size_t)16*1024*1024);
  u16* vh = (u16*)(ws + (size_t)32*1024*1024);
  u16* vt = (u16*)(ws + (size_t)48*1024*1024);
  u16* obuf = vh;

  proj_conv<<<dim3(512), dim3(256), 0, stream>>>(q, Wq, bq, qh);
  proj_conv<<<dim3(512), dim3(256), 0, stream>>>(k, Wk, bk, kh);
  proj_conv<<<dim3(512), dim3(256), 0, stream>>>(v, Wv, bv, vh);
  transpose_v<<<dim3(32, 4, 16), dim3(256), 0, stream>>>(vh, vt);
  attn_kernel<<<dim3(8, 16), dim3(256), 0, stream>>>(qh, kh, vt, obuf);
  conv_out<<<dim3(512), dim3(256), 0, stream>>>(obuf, Wo, bo, out);
}

// Round 2
// 294.888 us; speedup vs baseline: 7.9275x; 7.9275x over previous
//
#include <hip/hip_runtime.h>
#include <hip/hip_bf16.h>

typedef unsigned short u16;
typedef short s16x8 __attribute__((ext_vector_type(8)));
typedef u16 u16x8 __attribute__((ext_vector_type(8)));
typedef u16 u16x4 __attribute__((ext_vector_type(4)));
typedef float f32x4 __attribute__((ext_vector_type(4)));

__device__ __forceinline__ u16 f2bf(float f){
  unsigned x = __float_as_uint(f);
  unsigned r = (x + 0x7fffu + ((x >> 16) & 1u)) >> 16;  // RNE
  return (u16)r;
}
__device__ __forceinline__ float bf2f(u16 u){
  return __uint_as_float(((unsigned)u) << 16);
}

// ---------------------------------------------------------------------------
// Weight prep: W f32 [co][ci][3][3] -> Wt bf16 [tap][2][co][ci]  (hi, lo)
// Wt element count = 9*8192 = 73728 u16 (147456 B)
// ---------------------------------------------------------------------------
__global__ __launch_bounds__(256) void prep_w(
    const float* __restrict__ W, u16* __restrict__ Wt)
{
  int i = blockIdx.x * 256 + threadIdx.x;
  if (i >= 36864) return;
  int co = i / 576, rem = i % 576, ci = rem / 9, tap = rem % 9;
  float w = W[i];
  u16 hi = f2bf(w);
  float res = w - bf2f(hi);
  Wt[tap*8192 + co*64 + ci]        = hi;
  Wt[tap*8192 + 4096 + co*64 + ci] = f2bf(res);
}

// ---------------------------------------------------------------------------
// Implicit-GEMM 3x3 conv via MFMA 16x16x32 bf16. One WG (4 waves) per frame.
// Wave w owns pixel rows [w*4, w*4+4) (64 pixels), all 64 co.
// A = xT[pad_pixel][ci] bf16 in LDS (additive slot swizzle)
// B = Wt[tap][hi/lo][co][ci] bf16 from global (L2-resident, 144 KB)
// K = 9 taps x 64 ci = 576, as 18 MFMA k-steps x (hi+lo).
// ---------------------------------------------------------------------------
template<bool IN_F32, bool OUT_PROJ>
__global__ __launch_bounds__(256, 3) void conv_mfma(
    const void* __restrict__ xin, const u16* __restrict__ Wt,
    const float* __restrict__ bias, void* __restrict__ dst)
{
  __shared__ __align__(16) u16 xT[324 * 64];   // 41472 B
  const int tid = threadIdx.x;
  const int frame = blockIdx.x;

  // zero LDS (covers the pad border rows)
  for (int i = tid; i < 2592; i += 256)
    *(uint4*)((char*)xT + i*16) = make_uint4(0u, 0u, 0u, 0u);
  __syncthreads();

  // stage: thread = pixel, loop ci in packs of 8 -> swizzled ds_write_b128
  {
    const int p = tid, py = p >> 4, px = p & 15;
    const int pp = (py + 1)*18 + px + 1;
    const float* xf = (const float*)xin + (size_t)frame * 16384;
    const u16*   xb = (const u16*)  xin + (size_t)frame * 16384;
    #pragma unroll
    for (int cb = 0; cb < 8; ++cb){
      u16x8 pk;
      #pragma unroll
      for (int j = 0; j < 8; ++j){
        int ci = cb*8 + j;
        float xv = IN_F32 ? ((const float*)xf)[ci*256 + p] : bf2f(xb[ci*256 + p]);
        pk[j] = f2bf(xv);
      }
      unsigned off = (unsigned)(pp*128) + ((((unsigned)cb + (unsigned)pp) & 7u) << 4);
      *(u16x8*)((char*)xT + off) = pk;
    }
  }
  __syncthreads();

  const int w = tid >> 6, lane = tid & 63, lr = lane & 15, lg = lane >> 4;
  const int pyb = w * 4;                       // wave's base image row

  f32x4 acc[4][4];
  #pragma unroll
  for (int n = 0; n < 4; ++n){
    float b = bias[n*16 + lr];
    #pragma unroll
    for (int m = 0; m < 4; ++m){
      acc[m][n][0] = b; acc[m][n][1] = b; acc[m][n][2] = b; acc[m][n][3] = b;
    }
  }

  for (int dy = 0; dy < 3; ++dy){
    for (int dx = 0; dx < 3; ++dx){
      const u16* wt = Wt + (dy*3 + dx)*8192;
      #pragma unroll
      for (int kk = 0; kk < 2; ++kk){
        s16x8 bh[4], bl[4], af[4];
        #pragma unroll
        for (int n = 0; n < 4; ++n){
          const u16* wp = wt + (n*16 + lr)*64 + kk*32 + lg*8;
          bh[n] = *(const s16x8*)wp;
          bl[n] = *(const s16x8*)(wp + 4096);
        }
        #pragma unroll
        for (int m = 0; m < 4; ++m){
          int pp = (pyb + m + dy)*18 + lr + dx;
          unsigned slot = ((unsigned)(kk*4 + lg) + (unsigned)pp) & 7u;
          unsigned off = (unsigned)(pp*128) + (slot << 4);
          af[m] = *(const s16x8*)((const char*)xT + off);
        }
        #pragma unroll
        for (int m = 0; m < 4; ++m)
          #pragma unroll
          for (int n = 0; n < 4; ++n){
            acc[m][n] = __builtin_amdgcn_mfma_f32_16x16x32_bf16(af[m], bh[n], acc[m][n], 0,0,0);
            acc[m][n] = __builtin_amdgcn_mfma_f32_16x16x32_bf16(af[m], bl[n], acc[m][n], 0,0,0);
          }
      }
    }
  }

  // C/D layout: col(co) = lane&15, row(pixel) = (lane>>4)*4 + r  [verified]
  if (OUT_PROJ){
    u16* d = (u16*)dst;
    const int b = frame >> 8, sq = frame & 255;
    #pragma unroll
    for (int n = 0; n < 4; ++n){
      int co = n*16 + lr, h = co >> 3, dk = co & 7;
      size_t base = ((size_t)((b*8 + h)*256 + sq))*2048 + dk*256;
      #pragma unroll
      for (int m = 0; m < 4; ++m){
        int P = w*64 + m*16 + lg*4;
        u16x4 o4;
        #pragma unroll
        for (int r = 0; r < 4; ++r) o4[r] = f2bf(acc[m][n][r]);
        *(u16x4*)(d + base + P) = o4;
      }
    }
  } else {
    float* d = (float*)dst + (size_t)frame * 16384;
    #pragma unroll
    for (int n = 0; n < 4; ++n){
      int co = n*16 + lr;
      #pragma unroll
      for (int m = 0; m < 4; ++m){
        int P = w*64 + m*16 + lg*4;
        *(f32x4*)(d + co*256 + P) = acc[m][n];
      }
    }
  }
}

// ---------------------------------------------------------------------------
// V transpose: vh [bh][s][2048] -> vt [bh][d][256]
// ---------------------------------------------------------------------------
__global__ __launch_bounds__(256) void transpose_v(
    const u16* __restrict__ vh, u16* __restrict__ vt)
{
  __shared__ u16 tile[64][72];
  const int tid = threadIdx.x;
  const int dt = blockIdx.x, st = blockIdx.y, bh = blockIdx.z;
  {
    int r = tid >> 2, c4 = tid & 3;
    const u16* src = vh + ((size_t)(bh*256 + st*64 + r))*2048 + dt*64 + c4*16;
    uint4 v0 = *(const uint4*)src;
    uint4 v1 = *(const uint4*)(src + 8);
    *(uint4*)&tile[r][c4*16]     = v0;
    *(uint4*)&tile[r][c4*16 + 8] = v1;
  }
  __syncthreads();
  {
    int dr = tid >> 2, s4 = tid & 3;
    u16 tmp[16];
    #pragma unroll
    for (int i = 0; i < 16; ++i) tmp[i] = tile[s4*16 + i][dr];
    u16* dstp = vt + ((size_t)(bh*2048 + dt*64 + dr))*256 + st*64 + s4*16;
    *(uint4*)dstp       = *(uint4*)&tmp[0];
    *(uint4*)(dstp + 8) = *(uint4*)&tmp[8];
  }
}

// ---------------------------------------------------------------------------
// Attention (unchanged from R1, validated)
// ---------------------------------------------------------------------------
__global__ __launch_bounds__(256) void attn_kernel(
    const u16* __restrict__ qh, const u16* __restrict__ kh,
    const u16* __restrict__ vt, u16* __restrict__ obuf)
{
  const float SCALE = 0.022097086912079608f;   // 1/sqrt(2048)
  __shared__ __align__(16) u16 P[32*256];
  __shared__ float redA[4][32];
  __shared__ float redB[4][32];
  const int tid = threadIdx.x;
  const int w = tid >> 6, lane = tid & 63, lr = lane & 15, lg = lane >> 4;
  const int q0 = blockIdx.x * 32, bh = blockIdx.y, b = bh >> 3, h = bh & 7;
  const u16* Q = qh + ((size_t)(bh*256 + q0))*2048;
  const u16* K = kh + ((size_t)(bh*256 + w*64))*2048;
  const u16* V = vt + (size_t)bh * 2048 * 256;

  const f32x4 zero4 = {0.f, 0.f, 0.f, 0.f};
  f32x4 sacc[2][4];
  #pragma unroll
  for (int m = 0; m < 2; ++m)
    #pragma unroll
    for (int n = 0; n < 4; ++n) sacc[m][n] = zero4;

  for (int dstep = 0; dstep < 64; ++dstep){
    const int doff = dstep*32 + lg*8;
    s16x8 a0 = *(const s16x8*)(Q + (size_t)lr*2048 + doff);
    s16x8 a1 = *(const s16x8*)(Q + (size_t)(lr+16)*2048 + doff);
    #pragma unroll
    for (int n = 0; n < 4; ++n){
      s16x8 bk = *(const s16x8*)(K + (size_t)(n*16 + lr)*2048 + doff);
      sacc[0][n] = __builtin_amdgcn_mfma_f32_16x16x32_bf16(a0, bk, sacc[0][n], 0,0,0);
      sacc[1][n] = __builtin_amdgcn_mfma_f32_16x16x32_bf16(a1, bk, sacc[1][n], 0,0,0);
    }
  }

  float mx[2][4];
  #pragma unroll
  for (int m = 0; m < 2; ++m)
    #pragma unroll
    for (int r = 0; r < 4; ++r){
      float vv = fmaxf(fmaxf(sacc[m][0][r], sacc[m][1][r]),
                       fmaxf(sacc[m][2][r], sacc[m][3][r]));
      #pragma unroll
      for (int off = 1; off < 16; off <<= 1) vv = fmaxf(vv, __shfl_xor(vv, off));
      mx[m][r] = vv;
    }
  if (lr == 0){
    #pragma unroll
    for (int m = 0; m < 2; ++m)
      #pragma unroll
      for (int r = 0; r < 4; ++r) redA[w][m*16 + lg*4 + r] = mx[m][r];
  }
  __syncthreads();
  #pragma unroll
  for (int m = 0; m < 2; ++m)
    #pragma unroll
    for (int r = 0; r < 4; ++r){
      int row = m*16 + lg*4 + r;
      mx[m][r] = fmaxf(fmaxf(redA[0][row], redA[1][row]),
                       fmaxf(redA[2][row], redA[3][row]));
    }

  float sm[2][4];
  #pragma unroll
  for (int m = 0; m < 2; ++m)
    #pragma unroll
    for (int r = 0; r < 4; ++r) sm[m][r] = 0.f;
  #pragma unroll
  for (int m = 0; m < 2; ++m)
    #pragma unroll
    for (int n = 0; n < 4; ++n)
      #pragma unroll
      for (int r = 0; r < 4; ++r){
        float pv = __expf((sacc[m][n][r] - mx[m][r]) * SCALE);
        sm[m][r] += pv;
        int row = m*16 + lg*4 + r;
        int col = (w << 6) + (n << 4) + lr;
        unsigned off = (((unsigned)row << 9) + ((unsigned)col << 1))
                       ^ (unsigned)((row & 7) << 4);
        *(u16*)((char*)P + off) = f2bf(pv);
      }
  #pragma unroll
  for (int m = 0; m < 2; ++m)
    #pragma unroll
    for (int r = 0; r < 4; ++r){
      float vv = sm[m][r];
      #pragma unroll
      for (int off = 1; off < 16; off <<= 1) vv += __shfl_xor(vv, off);
      sm[m][r] = vv;
    }
  if (lr == 0){
    #pragma unroll
    for (int m = 0; m < 2; ++m)
      #pragma unroll
      for (int r = 0; r < 4; ++r) redB[w][m*16 + lg*4 + r] = sm[m][r];
  }
  __syncthreads();
  float rs[2][4];
  #pragma unroll
  for (int m = 0; m < 2; ++m)
    #pragma unroll
    for (int r = 0; r < 4; ++r){
      int row = m*16 + lg*4 + r;
      rs[m][r] = 1.0f / (redB[0][row] + redB[1][row] + redB[2][row] + redB[3][row]);
    }

  #pragma unroll 1
  for (int chunk = 0; chunk < 8; ++chunk){
    const int nb = w*512 + chunk*64;
    f32x4 oacc[2][4];
    #pragma unroll
    for (int m = 0; m < 2; ++m)
      #pragma unroll
      for (int n = 0; n < 4; ++n) oacc[m][n] = zero4;
    #pragma unroll
    for (int kt = 0; kt < 8; ++kt){
      unsigned koff = (unsigned)(kt*64 + lg*16);
      unsigned off0 = (((unsigned)lr << 9) + koff) ^ (unsigned)((lr & 7) << 4);
      unsigned off1 = (((unsigned)(lr+16) << 9) + koff) ^ (unsigned)(((lr+16) & 7) << 4);
      s16x8 a0 = *(const s16x8*)((const char*)P + off0);
      s16x8 a1 = *(const s16x8*)((const char*)P + off1);
      #pragma unroll
      for (int n = 0; n < 4; ++n){
        const u16* vp = V + (size_t)(nb + n*16 + lr)*256 + kt*32 + lg*8;
        s16x8 bv = *(const s16x8*)vp;
        oacc[0][n] = __builtin_amdgcn_mfma_f32_16x16x32_bf16(a0, bv, oacc[0][n], 0,0,0);
        oacc[1][n] = __builtin_amdgcn_mfma_f32_16x16x32_bf16(a1, bv, oacc[1][n], 0,0,0);
      }
    }
    #pragma unroll
    for (int m = 0; m < 2; ++m)
      #pragma unroll
      for (int n = 0; n < 4; ++n)
        #pragma unroll
        for (int r = 0; r < 4; ++r){
          float o = oacc[m][n][r] * rs[m][r];
          int qrow = q0 + m*16 + lg*4 + r;
          int d = nb + n*16 + lr;
          int frame = b*256 + qrow;
          int c = h*8 + (d >> 8);
          obuf[((size_t)(frame*64 + c))*256 + (d & 255)] = f2bf(o);
        }
  }
}

// ---------------------------------------------------------------------------
extern "C" void kernel_launch(void* const* d_in, const int* in_sizes, int n_in,
                              void* d_out, int out_size, void* d_ws, size_t ws_size,
                              hipStream_t stream)
{
  const float* q  = (const float*)d_in[0];
  const float* k  = (const float*)d_in[1];
  const float* v  = (const float*)d_in[2];
  const float* Wq = (const float*)d_in[3];
  const float* bq = (const float*)d_in[4];
  const float* Wk = (const float*)d_in[5];
  const float* bk = (const float*)d_in[6];
  const float* Wv = (const float*)d_in[7];
  const float* bv = (const float*)d_in[8];
  const float* Wo = (const float*)d_in[9];
  const float* bo = (const float*)d_in[10];
  float* out = (float*)d_out;

  // Workspace (64 MB): qh[0,16M) kh[16,32M) vh[32,48M) vt[48,64M)
  // WtQ/K/V live in the vt window until transpose_v overwrites it (they are
  // dead by then); WtO lives in qh after attn (qh dead). obuf reuses vh.
  char* ws = (char*)d_ws;
  u16* qh = (u16*)(ws);
  u16* kh = (u16*)(ws + (size_t)16*1024*1024);
  u16* vh = (u16*)(ws + (size_t)32*1024*1024);
  u16* vt = (u16*)(ws + (size_t)48*1024*1024);
  u16* obuf = vh;
  u16* WtQ = vt;
  u16* WtK = vt + 73728;
  u16* WtV = vt + 147456;
  u16* WtO = qh;

  prep_w<<<dim3(144), dim3(256), 0, stream>>>(Wq, WtQ);
  prep_w<<<dim3(144), dim3(256), 0, stream>>>(Wk, WtK);
  prep_w<<<dim3(144), dim3(256), 0, stream>>>(Wv, WtV);
  conv_mfma<true,  true ><<<dim3(512), dim3(256), 0, stream>>>(q, WtQ, bq, qh);
  conv_mfma<true,  true ><<<dim3(512), dim3(256), 0, stream>>>(k, WtK, bk, kh);
  conv_mfma<true,  true ><<<dim3(512), dim3(256), 0, stream>>>(v, WtV, bv, vh);
  transpose_v<<<dim3(32, 4, 16), dim3(256), 0, stream>>>(vh, vt);
  attn_kernel<<<dim3(8, 16), dim3(256), 0, stream>>>(qh, kh, vt, obuf);
  prep_w<<<dim3(144), dim3(256), 0, stream>>>(Wo, WtO);
  conv_mfma<false, false><<<dim3(512), dim3(256), 0, stream>>>(obuf, WtO, bo, out);
}

// Round 3
// 258.341 us; speedup vs baseline: 9.0491x; 1.1415x over previous
//
#include <hip/hip_runtime.h>
#include <hip/hip_bf16.h>

typedef unsigned short u16;
typedef short s16x8 __attribute__((ext_vector_type(8)));
typedef u16 u16x8 __attribute__((ext_vector_type(8)));
typedef u16 u16x4 __attribute__((ext_vector_type(4)));
typedef float f32x4 __attribute__((ext_vector_type(4)));

__device__ __forceinline__ u16 f2bf(float f){
  unsigned x = __float_as_uint(f);
  unsigned r = (x + 0x7fffu + ((x >> 16) & 1u)) >> 16;  // RNE
  return (u16)r;
}
__device__ __forceinline__ float bf2f(u16 u){
  return __uint_as_float(((unsigned)u) << 16);
}

// ---------------------------------------------------------------------------
// Weight prep: W f32 [co][ci][3][3] -> Wt bf16 [tap][2][co][ci]  (hi, lo)
// ---------------------------------------------------------------------------
__global__ __launch_bounds__(256) void prep_w(
    const float* __restrict__ W, u16* __restrict__ Wt)
{
  int i = blockIdx.x * 256 + threadIdx.x;
  if (i >= 36864) return;
  int co = i / 576, rem = i % 576, ci = rem / 9, tap = rem % 9;
  float w = W[i];
  u16 hi = f2bf(w);
  float res = w - bf2f(hi);
  Wt[tap*8192 + co*64 + ci]        = hi;
  Wt[tap*8192 + 4096 + co*64 + ci] = f2bf(res);
}

// ---------------------------------------------------------------------------
// Implicit-GEMM 3x3 conv via MFMA 16x16x32 bf16 (unchanged from R2, verified)
// ---------------------------------------------------------------------------
template<bool IN_F32, bool OUT_PROJ>
__global__ __launch_bounds__(256, 3) void conv_mfma(
    const void* __restrict__ xin, const u16* __restrict__ Wt,
    const float* __restrict__ bias, void* __restrict__ dst)
{
  __shared__ __align__(16) u16 xT[324 * 64];   // 41472 B
  const int tid = threadIdx.x;
  const int frame = blockIdx.x;

  for (int i = tid; i < 2592; i += 256)
    *(uint4*)((char*)xT + i*16) = make_uint4(0u, 0u, 0u, 0u);
  __syncthreads();

  {
    const int p = tid, py = p >> 4, px = p & 15;
    const int pp = (py + 1)*18 + px + 1;
    const float* xf = (const float*)xin + (size_t)frame * 16384;
    const u16*   xb = (const u16*)  xin + (size_t)frame * 16384;
    #pragma unroll
    for (int cb = 0; cb < 8; ++cb){
      u16x8 pk;
      #pragma unroll
      for (int j = 0; j < 8; ++j){
        int ci = cb*8 + j;
        float xv = IN_F32 ? ((const float*)xf)[ci*256 + p] : bf2f(xb[ci*256 + p]);
        pk[j] = f2bf(xv);
      }
      unsigned off = (unsigned)(pp*128) + ((((unsigned)cb + (unsigned)pp) & 7u) << 4);
      *(u16x8*)((char*)xT + off) = pk;
    }
  }
  __syncthreads();

  const int w = tid >> 6, lane = tid & 63, lr = lane & 15, lg = lane >> 4;
  const int pyb = w * 4;

  f32x4 acc[4][4];
  #pragma unroll
  for (int n = 0; n < 4; ++n){
    float b = bias[n*16 + lr];
    #pragma unroll
    for (int m = 0; m < 4; ++m){
      acc[m][n][0] = b; acc[m][n][1] = b; acc[m][n][2] = b; acc[m][n][3] = b;
    }
  }

  for (int dy = 0; dy < 3; ++dy){
    for (int dx = 0; dx < 3; ++dx){
      const u16* wt = Wt + (dy*3 + dx)*8192;
      #pragma unroll
      for (int kk = 0; kk < 2; ++kk){
        s16x8 bh[4], bl[4], af[4];
        #pragma unroll
        for (int n = 0; n < 4; ++n){
          const u16* wp = wt + (n*16 + lr)*64 + kk*32 + lg*8;
          bh[n] = *(const s16x8*)wp;
          bl[n] = *(const s16x8*)(wp + 4096);
        }
        #pragma unroll
        for (int m = 0; m < 4; ++m){
          int pp = (pyb + m + dy)*18 + lr + dx;
          unsigned slot = ((unsigned)(kk*4 + lg) + (unsigned)pp) & 7u;
          unsigned off = (unsigned)(pp*128) + (slot << 4);
          af[m] = *(const s16x8*)((const char*)xT + off);
        }
        #pragma unroll
        for (int m = 0; m < 4; ++m)
          #pragma unroll
          for (int n = 0; n < 4; ++n){
            acc[m][n] = __builtin_amdgcn_mfma_f32_16x16x32_bf16(af[m], bh[n], acc[m][n], 0,0,0);
            acc[m][n] = __builtin_amdgcn_mfma_f32_16x16x32_bf16(af[m], bl[n], acc[m][n], 0,0,0);
          }
      }
    }
  }

  if (OUT_PROJ){
    u16* d = (u16*)dst;
    const int b = frame >> 8, sq = frame & 255;
    #pragma unroll
    for (int n = 0; n < 4; ++n){
      int co = n*16 + lr, h = co >> 3, dk = co & 7;
      size_t base = ((size_t)((b*8 + h)*256 + sq))*2048 + dk*256;
      #pragma unroll
      for (int m = 0; m < 4; ++m){
        int P = w*64 + m*16 + lg*4;
        u16x4 o4;
        #pragma unroll
        for (int r = 0; r < 4; ++r) o4[r] = f2bf(acc[m][n][r]);
        *(u16x4*)(d + base + P) = o4;
      }
    }
  } else {
    float* d = (float*)dst + (size_t)frame * 16384;
    #pragma unroll
    for (int n = 0; n < 4; ++n){
      int co = n*16 + lr;
      #pragma unroll
      for (int m = 0; m < 4; ++m){
        int P = w*64 + m*16 + lg*4;
        *(f32x4*)(d + co*256 + P) = acc[m][n];
      }
    }
  }
}

// ---------------------------------------------------------------------------
// V transpose: vh [bh][s][2048] -> vt [bh][d][256]  (unchanged, verified)
// ---------------------------------------------------------------------------
__global__ __launch_bounds__(256) void transpose_v(
    const u16* __restrict__ vh, u16* __restrict__ vt)
{
  __shared__ u16 tile[64][72];
  const int tid = threadIdx.x;
  const int dt = blockIdx.x, st = blockIdx.y, bh = blockIdx.z;
  {
    int r = tid >> 2, c4 = tid & 3;
    const u16* src = vh + ((size_t)(bh*256 + st*64 + r))*2048 + dt*64 + c4*16;
    uint4 v0 = *(const uint4*)src;
    uint4 v1 = *(const uint4*)(src + 8);
    *(uint4*)&tile[r][c4*16]     = v0;
    *(uint4*)&tile[r][c4*16 + 8] = v1;
  }
  __syncthreads();
  {
    int dr = tid >> 2, s4 = tid & 3;
    u16 tmp[16];
    #pragma unroll
    for (int i = 0; i < 16; ++i) tmp[i] = tile[s4*16 + i][dr];
    u16* dstp = vt + ((size_t)(bh*2048 + dt*64 + dr))*256 + st*64 + s4*16;
    *(uint4*)dstp       = *(uint4*)&tmp[0];
    *(uint4*)(dstp + 8) = *(uint4*)&tmp[8];
  }
}

// ---------------------------------------------------------------------------
// Attention v2: grid 256 blocks (XCD-swizzled), 8 waves, q-tile = 16 rows.
// Wave w owns S-cols [w*32, w*32+32) and PV d-cols [w*256, (w+1)*256).
// Q staged in swizzled LDS (64 KB). Same verified fragment/swizzle patterns.
// ---------------------------------------------------------------------------
__global__ __launch_bounds__(512, 2) void attn_kernel(
    const u16* __restrict__ qh, const u16* __restrict__ kh,
    const u16* __restrict__ vt, u16* __restrict__ obuf)
{
  const float SCALE = 0.022097086912079608f;   // 1/sqrt(2048)
  __shared__ __align__(16) u16 Qs[16*2048];    // 65536 B, XOR-swizzled
  __shared__ __align__(16) u16 P[16*256];      // 8192 B,  XOR-swizzled
  __shared__ float redA[8][16];
  __shared__ float redB[8][16];
  const int tid = threadIdx.x;
  const int w = tid >> 6, lane = tid & 63, lr = lane & 15, lg = lane >> 4;

  // XCD-locality decode: all 16 blocks of a bh land on one XCD (2 bh/XCD,
  // 4 MB K+V working set = one XCD L2). Bijective.
  const int id = blockIdx.x;
  const int xcd = id & 7, j = id >> 3;
  const int bh = xcd + 8*(j & 1), qt = j >> 1;
  const int q0 = qt * 16, b = bh >> 3, h = bh & 7;

  const u16* Q = qh + ((size_t)(bh*256 + q0))*2048;
  const u16* K = kh + (size_t)bh * 256 * 2048;
  const u16* V = vt + (size_t)bh * 2048 * 256;

  // ---- stage Q into swizzled LDS (4096 x 16B chunks, 8 per thread) ----
  #pragma unroll
  for (int i = 0; i < 8; ++i){
    int c = tid + i*512;                       // 0..4095
    int row = c >> 8;
    unsigned colb = (unsigned)(c & 255) * 16;
    uint4 val = *(const uint4*)((const char*)Q + (size_t)row*4096 + colb);
    unsigned off = (((unsigned)row << 12) + colb) ^ (unsigned)((row & 7) << 4);
    *(uint4*)((char*)Qs + off) = val;
  }
  __syncthreads();

  // ---- S = Q K^T : per wave S[16 x 32] over d=2048 ----
  const f32x4 zero4 = {0.f, 0.f, 0.f, 0.f};
  f32x4 sacc[2] = {zero4, zero4};
  const int kbase = w * 32;
  #pragma unroll 8
  for (int dstep = 0; dstep < 64; ++dstep){
    unsigned aoff = (((unsigned)lr << 12) + (unsigned)(dstep*64 + lg*16))
                    ^ (unsigned)((lr & 7) << 4);
    s16x8 a = *(const s16x8*)((const char*)Qs + aoff);
    #pragma unroll
    for (int n = 0; n < 2; ++n){
      s16x8 bk = *(const s16x8*)(K + (size_t)(kbase + n*16 + lr)*2048 + dstep*32 + lg*8);
      sacc[n] = __builtin_amdgcn_mfma_f32_16x16x32_bf16(a, bk, sacc[n], 0,0,0);
    }
  }

  // ---- row max (16-lane shfl, then cross-wave over 8 waves via LDS) ----
  float mx[4];
  #pragma unroll
  for (int r = 0; r < 4; ++r){
    float vv = fmaxf(sacc[0][r], sacc[1][r]);
    #pragma unroll
    for (int off = 1; off < 16; off <<= 1) vv = fmaxf(vv, __shfl_xor(vv, off));
    mx[r] = vv;
  }
  if (lr == 0){
    #pragma unroll
    for (int r = 0; r < 4; ++r) redA[w][lg*4 + r] = mx[r];
  }
  __syncthreads();
  #pragma unroll
  for (int r = 0; r < 4; ++r){
    int row = lg*4 + r;
    float vv = redA[0][row];
    #pragma unroll
    for (int ww = 1; ww < 8; ++ww) vv = fmaxf(vv, redA[ww][row]);
    mx[r] = vv;
  }

  // ---- P = exp((S-max)*SCALE) -> swizzled LDS bf16 ; row sums ----
  float sm[4] = {0.f, 0.f, 0.f, 0.f};
  #pragma unroll
  for (int n = 0; n < 2; ++n)
    #pragma unroll
    for (int r = 0; r < 4; ++r){
      float pv = __expf((sacc[n][r] - mx[r]) * SCALE);
      sm[r] += pv;
      int row = lg*4 + r;
      int col = kbase + n*16 + lr;
      unsigned off = (((unsigned)row << 9) + ((unsigned)col << 1))
                     ^ (unsigned)((row & 7) << 4);
      *(u16*)((char*)P + off) = f2bf(pv);
    }
  #pragma unroll
  for (int r = 0; r < 4; ++r){
    float vv = sm[r];
    #pragma unroll
    for (int off = 1; off < 16; off <<= 1) vv += __shfl_xor(vv, off);
    sm[r] = vv;
  }
  if (lr == 0){
    #pragma unroll
    for (int r = 0; r < 4; ++r) redB[w][lg*4 + r] = sm[r];
  }
  __syncthreads();                             // fences P writes too
  float rs[4];
  #pragma unroll
  for (int r = 0; r < 4; ++r){
    int row = lg*4 + r;
    float s = redB[0][row];
    #pragma unroll
    for (int ww = 1; ww < 8; ++ww) s += redB[ww][row];
    rs[r] = 1.0f / s;
  }

  // ---- O = P V : per wave O[16 x 256] in 4 chunks of 64 d-cols ----
  #pragma unroll 1
  for (int chunk = 0; chunk < 4; ++chunk){
    const int nb = w*256 + chunk*64;
    f32x4 oacc[4] = {zero4, zero4, zero4, zero4};
    #pragma unroll
    for (int kt = 0; kt < 8; ++kt){
      unsigned aoff = (((unsigned)lr << 9) + (unsigned)(kt*64 + lg*16))
                      ^ (unsigned)((lr & 7) << 4);
      s16x8 pa = *(const s16x8*)((const char*)P + aoff);
      #pragma unroll
      for (int n = 0; n < 4; ++n){
        const u16* vp = V + (size_t)(nb + n*16 + lr)*256 + kt*32 + lg*8;
        s16x8 bv = *(const s16x8*)vp;
        oacc[n] = __builtin_amdgcn_mfma_f32_16x16x32_bf16(pa, bv, oacc[n], 0,0,0);
      }
    }
    #pragma unroll
    for (int n = 0; n < 4; ++n)
      #pragma unroll
      for (int r = 0; r < 4; ++r){
        float o = oacc[n][r] * rs[r];
        int qrow = q0 + lg*4 + r;
        int d = nb + n*16 + lr;
        int frame = b*256 + qrow;
        int c = h*8 + (d >> 8);
        obuf[((size_t)(frame*64 + c))*256 + (d & 255)] = f2bf(o);
      }
  }
}

// ---------------------------------------------------------------------------
extern "C" void kernel_launch(void* const* d_in, const int* in_sizes, int n_in,
                              void* d_out, int out_size, void* d_ws, size_t ws_size,
                              hipStream_t stream)
{
  const float* q  = (const float*)d_in[0];
  const float* k  = (const float*)d_in[1];
  const float* v  = (const float*)d_in[2];
  const float* Wq = (const float*)d_in[3];
  const float* bq = (const float*)d_in[4];
  const float* Wk = (const float*)d_in[5];
  const float* bk = (const float*)d_in[6];
  const float* Wv = (const float*)d_in[7];
  const float* bv = (const float*)d_in[8];
  const float* Wo = (const float*)d_in[9];
  const float* bo = (const float*)d_in[10];
  float* out = (float*)d_out;

  // Workspace (64 MB): qh[0,16M) kh[16,32M) vh[32,48M) vt[48,64M)
  char* ws = (char*)d_ws;
  u16* qh = (u16*)(ws);
  u16* kh = (u16*)(ws + (size_t)16*1024*1024);
  u16* vh = (u16*)(ws + (size_t)32*1024*1024);
  u16* vt = (u16*)(ws + (size_t)48*1024*1024);
  u16* obuf = vh;
  u16* WtQ = vt;
  u16* WtK = vt + 73728;
  u16* WtV = vt + 147456;
  u16* WtO = qh;

  prep_w<<<dim3(144), dim3(256), 0, stream>>>(Wq, WtQ);
  prep_w<<<dim3(144), dim3(256), 0, stream>>>(Wk, WtK);
  prep_w<<<dim3(144), dim3(256), 0, stream>>>(Wv, WtV);
  conv_mfma<true,  true ><<<dim3(512), dim3(256), 0, stream>>>(q, WtQ, bq, qh);
  conv_mfma<true,  true ><<<dim3(512), dim3(256), 0, stream>>>(k, WtK, bk, kh);
  conv_mfma<true,  true ><<<dim3(512), dim3(256), 0, stream>>>(v, WtV, bv, vh);
  transpose_v<<<dim3(32, 4, 16), dim3(256), 0, stream>>>(vh, vt);
  attn_kernel<<<dim3(256), dim3(512), 0, stream>>>(qh, kh, vt, obuf);
  prep_w<<<dim3(144), dim3(256), 0, stream>>>(Wo, WtO);
  conv_mfma<false, false><<<dim3(512), dim3(256), 0, stream>>>(obuf, WtO, bo, out);
}

// Round 4
// 226.292 us; speedup vs baseline: 10.3307x; 1.1416x over previous
//
#include <hip/hip_runtime.h>
#include <hip/hip_bf16.h>

typedef unsigned short u16;
typedef short s16x8 __attribute__((ext_vector_type(8)));
typedef u16 u16x8 __attribute__((ext_vector_type(8)));
typedef u16 u16x4 __attribute__((ext_vector_type(4)));
typedef float f32x4 __attribute__((ext_vector_type(4)));

__device__ __forceinline__ u16 f2bf(float f){
  unsigned x = __float_as_uint(f);
  unsigned r = (x + 0x7fffu + ((x >> 16) & 1u)) >> 16;  // RNE
  return (u16)r;
}
__device__ __forceinline__ float bf2f(u16 u){
  return __uint_as_float(((unsigned)u) << 16);
}

// async 16B global -> LDS (dest = wave-uniform base + lane*16; src per-lane)
__device__ __forceinline__ void cp16_async(const u16* g, u16* l){
  __builtin_amdgcn_global_load_lds(
      (const __attribute__((address_space(1))) unsigned int*)g,
      (__attribute__((address_space(3))) unsigned int*)l,
      16, 0, 0);
}

// ---------------------------------------------------------------------------
// Weight prep: W f32 [co][ci][3][3] -> Wt bf16 [tap][2][co][ci]  (hi, lo)
// ---------------------------------------------------------------------------
__device__ __forceinline__ void prep_w_body(const float* W, u16* Wt, int i){
  if (i >= 36864) return;
  int co = i / 576, rem = i % 576, ci = rem / 9, tap = rem % 9;
  float w = W[i];
  u16 hi = f2bf(w);
  float res = w - bf2f(hi);
  Wt[tap*8192 + co*64 + ci]        = hi;
  Wt[tap*8192 + 4096 + co*64 + ci] = f2bf(res);
}

__global__ __launch_bounds__(256) void prep_w3(
    const float* __restrict__ Wq, const float* __restrict__ Wk,
    const float* __restrict__ Wv, u16* __restrict__ Wt)
{
  int which = blockIdx.y;
  const float* W = (which == 0) ? Wq : (which == 1) ? Wk : Wv;
  prep_w_body(W, Wt + which*73728, blockIdx.x * 256 + threadIdx.x);
}

__global__ __launch_bounds__(256) void prep_w(
    const float* __restrict__ W, u16* __restrict__ Wt)
{
  prep_w_body(W, Wt, blockIdx.x * 256 + threadIdx.x);
}

// ---------------------------------------------------------------------------
// Implicit-GEMM 3x3 conv body (validated in R2/R3, unchanged)
// ---------------------------------------------------------------------------
template<bool IN_F32, bool OUT_PROJ>
__device__ __forceinline__ void conv_body(
    const void* __restrict__ xin, const u16* __restrict__ Wt,
    const float* __restrict__ bias, void* __restrict__ dst,
    int frame, u16* xT, int tid)
{
  for (int i = tid; i < 2592; i += 256)
    *(uint4*)((char*)xT + i*16) = make_uint4(0u, 0u, 0u, 0u);
  __syncthreads();

  {
    const int p = tid, py = p >> 4, px = p & 15;
    const int pp = (py + 1)*18 + px + 1;
    const float* xf = (const float*)xin + (size_t)frame * 16384;
    const u16*   xb = (const u16*)  xin + (size_t)frame * 16384;
    #pragma unroll
    for (int cb = 0; cb < 8; ++cb){
      u16x8 pk;
      #pragma unroll
      for (int j = 0; j < 8; ++j){
        int ci = cb*8 + j;
        float xv = IN_F32 ? ((const float*)xf)[ci*256 + p] : bf2f(xb[ci*256 + p]);
        pk[j] = f2bf(xv);
      }
      unsigned off = (unsigned)(pp*128) + ((((unsigned)cb + (unsigned)pp) & 7u) << 4);
      *(u16x8*)((char*)xT + off) = pk;
    }
  }
  __syncthreads();

  const int w = tid >> 6, lane = tid & 63, lr = lane & 15, lg = lane >> 4;
  const int pyb = w * 4;

  f32x4 acc[4][4];
  #pragma unroll
  for (int n = 0; n < 4; ++n){
    float b = bias[n*16 + lr];
    #pragma unroll
    for (int m = 0; m < 4; ++m){
      acc[m][n][0] = b; acc[m][n][1] = b; acc[m][n][2] = b; acc[m][n][3] = b;
    }
  }

  for (int dy = 0; dy < 3; ++dy){
    for (int dx = 0; dx < 3; ++dx){
      const u16* wt = Wt + (dy*3 + dx)*8192;
      #pragma unroll
      for (int kk = 0; kk < 2; ++kk){
        s16x8 bh[4], bl[4], af[4];
        #pragma unroll
        for (int n = 0; n < 4; ++n){
          const u16* wp = wt + (n*16 + lr)*64 + kk*32 + lg*8;
          bh[n] = *(const s16x8*)wp;
          bl[n] = *(const s16x8*)(wp + 4096);
        }
        #pragma unroll
        for (int m = 0; m < 4; ++m){
          int pp = (pyb + m + dy)*18 + lr + dx;
          unsigned slot = ((unsigned)(kk*4 + lg) + (unsigned)pp) & 7u;
          unsigned off = (unsigned)(pp*128) + (slot << 4);
          af[m] = *(const s16x8*)((const char*)xT + off);
        }
        #pragma unroll
        for (int m = 0; m < 4; ++m)
          #pragma unroll
          for (int n = 0; n < 4; ++n){
            acc[m][n] = __builtin_amdgcn_mfma_f32_16x16x32_bf16(af[m], bh[n], acc[m][n], 0,0,0);
            acc[m][n] = __builtin_amdgcn_mfma_f32_16x16x32_bf16(af[m], bl[n], acc[m][n], 0,0,0);
          }
      }
    }
  }

  if (OUT_PROJ){
    u16* d = (u16*)dst;
    const int b = frame >> 8, sq = frame & 255;
    #pragma unroll
    for (int n = 0; n < 4; ++n){
      int co = n*16 + lr, h = co >> 3, dk = co & 7;
      size_t base = ((size_t)((b*8 + h)*256 + sq))*2048 + dk*256;
      #pragma unroll
      for (int m = 0; m < 4; ++m){
        int P = w*64 + m*16 + lg*4;
        u16x4 o4;
        #pragma unroll
        for (int r = 0; r < 4; ++r) o4[r] = f2bf(acc[m][n][r]);
        *(u16x4*)(d + base + P) = o4;
      }
    }
  } else {
    float* d = (float*)dst + (size_t)frame * 16384;
    #pragma unroll
    for (int n = 0; n < 4; ++n){
      int co = n*16 + lr;
      #pragma unroll
      for (int m = 0; m < 4; ++m){
        int P = w*64 + m*16 + lg*4;
        *(f32x4*)(d + co*256 + P) = acc[m][n];
      }
    }
  }
}

// merged q/k/v projection convs: grid 1536 (which = blockIdx.x>>9)
__global__ __launch_bounds__(256, 3) void conv3_mfma(
    const float* __restrict__ q, const float* __restrict__ k,
    const float* __restrict__ v, const u16* __restrict__ Wt3,
    const float* __restrict__ bq, const float* __restrict__ bk,
    const float* __restrict__ bv,
    u16* __restrict__ qh, u16* __restrict__ kh, u16* __restrict__ vh)
{
  __shared__ __align__(16) u16 xT[324 * 64];
  const int which = blockIdx.x >> 9;
  const int frame = blockIdx.x & 511;
  const float* x = (which == 0) ? q : (which == 1) ? k : v;
  const float* bias = (which == 0) ? bq : (which == 1) ? bk : bv;
  u16* dst = (which == 0) ? qh : (which == 1) ? kh : vh;
  conv_body<true, true>(x, Wt3 + which*73728, bias, dst, frame, xT, threadIdx.x);
}

__global__ __launch_bounds__(256, 3) void conv_out_mfma(
    const u16* __restrict__ xin, const u16* __restrict__ Wt,
    const float* __restrict__ bias, float* __restrict__ out)
{
  __shared__ __align__(16) u16 xT[324 * 64];
  conv_body<false, false>(xin, Wt, bias, out, blockIdx.x, xT, threadIdx.x);
}

// ---------------------------------------------------------------------------
// V transpose: vh [bh][s][2048] -> vt [bh][d][256]  (unchanged, verified)
// ---------------------------------------------------------------------------
__global__ __launch_bounds__(256) void transpose_v(
    const u16* __restrict__ vh, u16* __restrict__ vt)
{
  __shared__ u16 tile[64][72];
  const int tid = threadIdx.x;
  const int dt = blockIdx.x, st = blockIdx.y, bh = blockIdx.z;
  {
    int r = tid >> 2, c4 = tid & 3;
    const u16* src = vh + ((size_t)(bh*256 + st*64 + r))*2048 + dt*64 + c4*16;
    uint4 v0 = *(const uint4*)src;
    uint4 v1 = *(const uint4*)(src + 8);
    *(uint4*)&tile[r][c4*16]     = v0;
    *(uint4*)&tile[r][c4*16 + 8] = v1;
  }
  __syncthreads();
  {
    int dr = tid >> 2, s4 = tid & 3;
    u16 tmp[16];
    #pragma unroll
    for (int i = 0; i < 16; ++i) tmp[i] = tile[s4*16 + i][dr];
    u16* dstp = vt + ((size_t)(bh*2048 + dt*64 + dr))*256 + st*64 + s4*16;
    *(uint4*)dstp       = *(uint4*)&tmp[0];
    *(uint4*)(dstp + 8) = *(uint4*)&tmp[8];
  }
}

// ---------------------------------------------------------------------------
// Attention v3: 256 blocks (XCD-swizzled), 8 waves, q-tile = 16 rows.
// K and V staged through double-buffered LDS via global_load_lds with
// pre-swizzled global sources (linear LDS dest, XOR-swizzled read).
// One __syncthreads per chunk = implicit vmcnt(0) drain (pipeline wait).
// ---------------------------------------------------------------------------
__global__ __launch_bounds__(512, 2) void attn_kernel(
    const u16* __restrict__ qh, const u16* __restrict__ kh,
    const u16* __restrict__ vt, u16* __restrict__ obuf)
{
  const float SCALE = 0.022097086912079608f;   // 1/sqrt(2048)
  __shared__ __align__(16) u16 Qs[16*2048];    // 64 KB; reused as V buf 0
  __shared__ __align__(16) u16 Kb[2][16384];   // 2 x 32 KB; reused as V buf 1
  __shared__ __align__(16) u16 P[16*256];      // 8 KB
  __shared__ float redA[8][16];
  __shared__ float redB[8][16];

  const int tid = threadIdx.x;
  const int w = tid >> 6, lane = tid & 63, lr = lane & 15, lg = lane >> 4;

  // XCD-locality decode (bijective over 256 blocks; 2 bh per XCD)
  const int id = blockIdx.x;
  const int xcd = id & 7, j = id >> 3;
  const int bh = xcd + 8*(j & 1), qt = j >> 1;
  const int q0 = qt * 16, b = bh >> 3, h = bh & 7;

  const u16* Qg = qh + ((size_t)(bh*256 + q0))*2048;
  const u16* Kg = kh + (size_t)bh * 256 * 2048;
  const u16* Vg = vt + (size_t)bh * 2048 * 256;

  // ---- K chunk stage: tile [256 k-rows][64 d] = 32KB, rows 128B, swizzled
  const int spK = (lane & 7) ^ ((lane >> 3) & 7);
  #define STAGE_K(c, buf)                                                   \
    _Pragma("unroll")                                                       \
    for (int r_ = 0; r_ < 4; ++r_)                                          \
      cp16_async(Kg + (size_t)(w*32 + r_*8 + (lane>>3))*2048 + (c)*64 + spK*8, \
                 (buf) + w*2048 + r_*512);

  // ---- V chunk stage: tile [128 d-rows][256 s] = 64KB, rows 512B, swizzled
  #define STAGE_V(c, buf)                                                   \
    _Pragma("unroll")                                                       \
    for (int r_ = 0; r_ < 8; ++r_){                                         \
      int rl_ = w*16 + r_*2 + (lane>>5);                                    \
      int sp_ = (lane & 31) ^ (rl_ & 7);                                    \
      cp16_async(Vg + (size_t)((c)*128 + rl_)*256 + sp_*8,                  \
                 (buf) + w*4096 + r_*512);                                  \
    }

  // ---- stage Qs (swizzled, via pre-swizzled source) + K chunk 0 ----
  #pragma unroll
  for (int r = 0; r < 8; ++r){
    int t = r*64 + lane;
    int row = w*2 + (t >> 8);
    int dp = t & 255;
    int sp = (dp & ~7) | ((dp & 7) ^ (row & 7));
    cp16_async(Qg + (size_t)row*2048 + sp*8, Qs + w*4096 + r*512);
  }
  STAGE_K(0, Kb[0]);
  __syncthreads();

  // ---- S = Q K^T : 32 d-chunks, 2-phase pipelined ----
  const f32x4 zero4 = {0.f, 0.f, 0.f, 0.f};
  f32x4 sacc[2] = {zero4, zero4};
  #pragma unroll 1
  for (int c = 0; c < 32; ++c){
    if (c < 31) STAGE_K(c+1, Kb[(c+1)&1]);
    const u16* kb = Kb[c&1];
    #pragma unroll
    for (int d2 = 0; d2 < 2; ++d2){
      unsigned aoff = (((unsigned)lr << 12) + (unsigned)(c*128 + d2*64 + lg*16))
                      ^ (unsigned)((lr & 7) << 4);
      s16x8 a = *(const s16x8*)((const char*)Qs + aoff);
      #pragma unroll
      for (int n = 0; n < 2; ++n){
        int row = w*32 + n*16 + lr;
        const u16* kp = kb + row*64 + (((d2*4 + lg) ^ (row & 7)) << 3);
        s16x8 bk = *(const s16x8*)kp;
        sacc[n] = __builtin_amdgcn_mfma_f32_16x16x32_bf16(a, bk, sacc[n], 0,0,0);
      }
    }
    __syncthreads();
  }

  // ---- row max (16-lane shfl, then cross-wave over 8 waves) ----
  float mx[4];
  #pragma unroll
  for (int r = 0; r < 4; ++r){
    float vv = fmaxf(sacc[0][r], sacc[1][r]);
    #pragma unroll
    for (int off = 1; off < 16; off <<= 1) vv = fmaxf(vv, __shfl_xor(vv, off));
    mx[r] = vv;
  }
  if (lr == 0){
    #pragma unroll
    for (int r = 0; r < 4; ++r) redA[w][lg*4 + r] = mx[r];
  }
  __syncthreads();
  #pragma unroll
  for (int r = 0; r < 4; ++r){
    int row = lg*4 + r;
    float vv = redA[0][row];
    #pragma unroll
    for (int ww = 1; ww < 8; ++ww) vv = fmaxf(vv, redA[ww][row]);
    mx[r] = vv;
  }

  // ---- P = exp((S-max)*SCALE) -> swizzled LDS bf16 ; row sums ----
  const int kbase = w * 32;
  float sm[4] = {0.f, 0.f, 0.f, 0.f};
  #pragma unroll
  for (int n = 0; n < 2; ++n)
    #pragma unroll
    for (int r = 0; r < 4; ++r){
      float pv = __expf((sacc[n][r] - mx[r]) * SCALE);
      sm[r] += pv;
      int row = lg*4 + r;
      int col = kbase + n*16 + lr;
      unsigned off = (((unsigned)row << 9) + ((unsigned)col << 1))
                     ^ (unsigned)((row & 7) << 4);
      *(u16*)((char*)P + off) = f2bf(pv);
    }
  #pragma unroll
  for (int r = 0; r < 4; ++r){
    float vv = sm[r];
    #pragma unroll
    for (int off = 1; off < 16; off <<= 1) vv += __shfl_xor(vv, off);
    sm[r] = vv;
  }
  if (lr == 0){
    #pragma unroll
    for (int r = 0; r < 4; ++r) redB[w][lg*4 + r] = sm[r];
  }
  __syncthreads();                             // fences P + redB; Qs/Kb now dead
  float rs[4];
  #pragma unroll
  for (int r = 0; r < 4; ++r){
    int row = lg*4 + r;
    float s = redB[0][row];
    #pragma unroll
    for (int ww = 1; ww < 8; ++ww) s += redB[ww][row];
    rs[r] = 1.0f / s;
  }

  // ---- O = P V : 16 d-chunks (128 d each), 2-phase pipelined ----
  u16* Vb0 = Qs;                               // reuse (dead after QK^T)
  u16* Vb1 = &Kb[0][0];
  STAGE_V(0, Vb0);
  __syncthreads();
  #pragma unroll 1
  for (int c = 0; c < 16; ++c){
    if (c < 15){
      u16* nbuf = ((c+1) & 1) ? Vb1 : Vb0;
      STAGE_V(c+1, nbuf);
    }
    const u16* vb = (c & 1) ? Vb1 : Vb0;
    f32x4 oacc = zero4;
    #pragma unroll
    for (int kt = 0; kt < 8; ++kt){
      unsigned poff = (((unsigned)lr << 9) + (unsigned)(kt*64 + lg*16))
                      ^ (unsigned)((lr & 7) << 4);
      s16x8 pa = *(const s16x8*)((const char*)P + poff);
      int row = w*16 + lr;
      const u16* vp = vb + row*256 + (((kt*4 + lg) ^ (row & 7)) << 3);
      s16x8 bv = *(const s16x8*)vp;
      oacc = __builtin_amdgcn_mfma_f32_16x16x32_bf16(pa, bv, oacc, 0,0,0);
    }
    #pragma unroll
    for (int r = 0; r < 4; ++r){
      float o = oacc[r] * rs[r];
      int qrow = q0 + lg*4 + r;
      int d = c*128 + w*16 + lr;
      int frame = b*256 + qrow;
      int cdim = h*8 + (d >> 8);
      obuf[((size_t)(frame*64 + cdim))*256 + (d & 255)] = f2bf(o);
    }
    __syncthreads();
  }
  #undef STAGE_K
  #undef STAGE_V
}

// ---------------------------------------------------------------------------
extern "C" void kernel_launch(void* const* d_in, const int* in_sizes, int n_in,
                              void* d_out, int out_size, void* d_ws, size_t ws_size,
                              hipStream_t stream)
{
  const float* q  = (const float*)d_in[0];
  const float* k  = (const float*)d_in[1];
  const float* v  = (const float*)d_in[2];
  const float* Wq = (const float*)d_in[3];
  const float* bq = (const float*)d_in[4];
  const float* Wk = (const float*)d_in[5];
  const float* bk = (const float*)d_in[6];
  const float* Wv = (const float*)d_in[7];
  const float* bv = (const float*)d_in[8];
  const float* Wo = (const float*)d_in[9];
  const float* bo = (const float*)d_in[10];
  float* out = (float*)d_out;

  // Workspace (64 MB): qh[0,16M) kh[16,32M) vh[32,48M) vt[48,64M)
  char* ws = (char*)d_ws;
  u16* qh = (u16*)(ws);
  u16* kh = (u16*)(ws + (size_t)16*1024*1024);
  u16* vh = (u16*)(ws + (size_t)32*1024*1024);
  u16* vt = (u16*)(ws + (size_t)48*1024*1024);
  u16* obuf = vh;          // attn output frames (vh dead after transpose_v)
  u16* Wt3  = vt;          // 3 weight packs; dead before transpose_v clobbers
  u16* WtO  = qh;          // qh dead after attn

  prep_w3<<<dim3(144, 3), dim3(256), 0, stream>>>(Wq, Wk, Wv, Wt3);
  conv3_mfma<<<dim3(1536), dim3(256), 0, stream>>>(q, k, v, Wt3, bq, bk, bv,
                                                   qh, kh, vh);
  transpose_v<<<dim3(32, 4, 16), dim3(256), 0, stream>>>(vh, vt);
  attn_kernel<<<dim3(256), dim3(512), 0, stream>>>(qh, kh, vt, obuf);
  prep_w<<<dim3(144), dim3(256), 0, stream>>>(Wo, WtO);
  conv_out_mfma<<<dim3(512), dim3(256), 0, stream>>>(obuf, WtO, bo, out);
}

// Round 5
// 147.915 us; speedup vs baseline: 15.8046x; 1.5299x over previous
//
#include <hip/hip_runtime.h>
#include <hip/hip_bf16.h>

typedef unsigned short u16;
typedef short s16x8 __attribute__((ext_vector_type(8)));
typedef u16 u16x8 __attribute__((ext_vector_type(8)));
typedef u16 u16x4 __attribute__((ext_vector_type(4)));
typedef float f32x4 __attribute__((ext_vector_type(4)));

__device__ __forceinline__ u16 f2bf(float f){
  unsigned x = __float_as_uint(f);
  unsigned r = (x + 0x7fffu + ((x >> 16) & 1u)) >> 16;  // RNE
  return (u16)r;
}
__device__ __forceinline__ float bf2f(u16 u){
  return __uint_as_float(((unsigned)u) << 16);
}

// async 16B global -> LDS (dest = wave-uniform base + lane*16; src per-lane)
__device__ __forceinline__ void cp16_async(const u16* g, u16* l){
  __builtin_amdgcn_global_load_lds(
      (const __attribute__((address_space(1))) unsigned int*)g,
      (__attribute__((address_space(3))) unsigned int*)l,
      16, 0, 0);
}

// ---------------------------------------------------------------------------
// Weight prep v2: W f32 [co][ci][3][3] ->
//   Wt bf16 [step=tap*2+kk][co][8 slots x 8 u16], slots PRE-SWIZZLED:
//   logical slot l (0-3 = hi ci kk*32+8l.., 4-7 = lo) stored at l^(co&7).
//   DMA-ready: conv stages one 8 KB step linearly into LDS, reads swizzled.
// ---------------------------------------------------------------------------
__device__ __forceinline__ void prep_w_body(const float* W, u16* Wt, int i){
  if (i >= 36864) return;
  int co = i / 576, rem = i % 576, ci = rem / 9, tap = rem % 9;
  float w = W[i];
  u16 hi = f2bf(w);
  float res = w - bf2f(hi);
  int kk = ci >> 5, j = ci & 31;
  int sh = (j >> 3) ^ (co & 7);          // phys slot, hi half
  int sl = ((j >> 3) + 4) ^ (co & 7);    // phys slot, lo half
  int base = ((tap*2 + kk)*64 + co)*64;
  Wt[base + sh*8 + (j & 7)] = hi;
  Wt[base + sl*8 + (j & 7)] = f2bf(res);
}

__global__ __launch_bounds__(256) void prep_w3(
    const float* __restrict__ Wq, const float* __restrict__ Wk,
    const float* __restrict__ Wv, u16* __restrict__ Wt)
{
  int which = blockIdx.y;
  const float* W = (which == 0) ? Wq : (which == 1) ? Wk : Wv;
  prep_w_body(W, Wt + which*73728, blockIdx.x * 256 + threadIdx.x);
}

__global__ __launch_bounds__(256) void prep_w(
    const float* __restrict__ W, u16* __restrict__ Wt)
{
  prep_w_body(W, Wt, blockIdx.x * 256 + threadIdx.x);
}

// ---------------------------------------------------------------------------
// Implicit-GEMM 3x3 conv v2: B (weights) double-buffered through LDS via
// global_load_lds (8 KB per K-step, shared by all 4 waves) — attn-v3 pattern.
// MFMA operand sequence identical to the validated R2-R4 body.
// ---------------------------------------------------------------------------
template<bool IN_F32, bool OUT_PROJ>
__device__ __forceinline__ void conv_body(
    const void* __restrict__ xin, const u16* __restrict__ Wt,
    const float* __restrict__ bias, void* __restrict__ dst,
    int frame, u16* xT, u16* Bb, int tid)
{
  #define STAGE_B(s, buf) do {                                   \
    const u16* src_ = Wt + (s)*4096;                             \
    cp16_async(src_ + tid*8, (buf) + tid*8);                     \
    cp16_async(src_ + 2048 + tid*8, (buf) + 2048 + tid*8);       \
  } while(0)

  // zero xT (covers pad border)
  for (int i = tid; i < 2592; i += 256)
    *(uint4*)((char*)xT + i*16) = make_uint4(0u, 0u, 0u, 0u);
  __syncthreads();

  // stage B step 0 (DMA, overlaps the scalar x-staging below)
  STAGE_B(0, Bb);

  // stage x: thread = pixel, gather 64 ci -> swizzled ds_write_b128
  {
    const int p = tid, py = p >> 4, px = p & 15;
    const int pp = (py + 1)*18 + px + 1;
    const float* xf = (const float*)xin + (size_t)frame * 16384;
    const u16*   xb = (const u16*)  xin + (size_t)frame * 16384;
    #pragma unroll
    for (int cb = 0; cb < 8; ++cb){
      u16x8 pk;
      #pragma unroll
      for (int j = 0; j < 8; ++j){
        int ci = cb*8 + j;
        float xv = IN_F32 ? ((const float*)xf)[ci*256 + p] : bf2f(xb[ci*256 + p]);
        pk[j] = f2bf(xv);
      }
      unsigned off = (unsigned)(pp*128) + ((((unsigned)cb + (unsigned)pp) & 7u) << 4);
      *(u16x8*)((char*)xT + off) = pk;
    }
  }
  __syncthreads();                       // drains STAGE_B(0) DMA too

  const int w = tid >> 6, lane = tid & 63, lr = lane & 15, lg = lane >> 4;
  const int pyb = w * 4;

  f32x4 acc[4][4];
  #pragma unroll
  for (int n = 0; n < 4; ++n){
    float b = bias[n*16 + lr];
    #pragma unroll
    for (int m = 0; m < 4; ++m){
      acc[m][n][0] = b; acc[m][n][1] = b; acc[m][n][2] = b; acc[m][n][3] = b;
    }
  }

  u16* Bbuf0 = Bb;
  u16* Bbuf1 = Bb + 4096;
  #pragma unroll 1
  for (int step = 0; step < 18; ++step){
    if (step < 17) STAGE_B(step + 1, ((step + 1) & 1) ? Bbuf1 : Bbuf0);
    const u16* bb = (step & 1) ? Bbuf1 : Bbuf0;
    const int tap = step >> 1, kk = step & 1;
    const int dy = tap / 3, dx = tap - dy*3;

    s16x8 bhf[4], blf[4], af[4];
    #pragma unroll
    for (int n = 0; n < 4; ++n){
      int co = n*16 + lr;
      bhf[n] = *(const s16x8*)(bb + co*64 + (( lg      ^ (co & 7)) << 3));
      blf[n] = *(const s16x8*)(bb + co*64 + (((lg + 4) ^ (co & 7)) << 3));
    }
    #pragma unroll
    for (int m = 0; m < 4; ++m){
      int pp = (pyb + m + dy)*18 + lr + dx;
      unsigned slot = ((unsigned)(kk*4 + lg) + (unsigned)pp) & 7u;
      af[m] = *(const s16x8*)((const char*)xT + (unsigned)(pp*128) + (slot << 4));
    }
    #pragma unroll
    for (int m = 0; m < 4; ++m)
      #pragma unroll
      for (int n = 0; n < 4; ++n){
        acc[m][n] = __builtin_amdgcn_mfma_f32_16x16x32_bf16(af[m], bhf[n], acc[m][n], 0,0,0);
        acc[m][n] = __builtin_amdgcn_mfma_f32_16x16x32_bf16(af[m], blf[n], acc[m][n], 0,0,0);
      }
    __syncthreads();
  }
  #undef STAGE_B

  // C/D layout: col(co) = lane&15, row(pixel) = (lane>>4)*4 + r  [verified]
  if (OUT_PROJ){
    u16* d = (u16*)dst;
    const int b = frame >> 8, sq = frame & 255;
    #pragma unroll
    for (int n = 0; n < 4; ++n){
      int co = n*16 + lr, h = co >> 3, dk = co & 7;
      size_t base = ((size_t)((b*8 + h)*256 + sq))*2048 + dk*256;
      #pragma unroll
      for (int m = 0; m < 4; ++m){
        int P = w*64 + m*16 + lg*4;
        u16x4 o4;
        #pragma unroll
        for (int r = 0; r < 4; ++r) o4[r] = f2bf(acc[m][n][r]);
        *(u16x4*)(d + base + P) = o4;
      }
    }
  } else {
    float* d = (float*)dst + (size_t)frame * 16384;
    #pragma unroll
    for (int n = 0; n < 4; ++n){
      int co = n*16 + lr;
      #pragma unroll
      for (int m = 0; m < 4; ++m){
        int P = w*64 + m*16 + lg*4;
        *(f32x4*)(d + co*256 + P) = acc[m][n];
      }
    }
  }
}

// merged q/k/v projection convs: grid 1536 (which = blockIdx.x>>9)
__global__ __launch_bounds__(256, 2) void conv3_mfma(
    const float* __restrict__ q, const float* __restrict__ k,
    const float* __restrict__ v, const u16* __restrict__ Wt3,
    const float* __restrict__ bq, const float* __restrict__ bk,
    const float* __restrict__ bv,
    u16* __restrict__ qh, u16* __restrict__ kh, u16* __restrict__ vh)
{
  __shared__ __align__(16) u16 xT[324 * 64];
  __shared__ __align__(16) u16 Bb[2 * 4096];
  const int which = blockIdx.x >> 9;
  const int frame = blockIdx.x & 511;
  const float* x = (which == 0) ? q : (which == 1) ? k : v;
  const float* bias = (which == 0) ? bq : (which == 1) ? bk : bv;
  u16* dst = (which == 0) ? qh : (which == 1) ? kh : vh;
  conv_body<true, true>(x, Wt3 + which*73728, bias, dst, frame, xT, Bb, threadIdx.x);
}

__global__ __launch_bounds__(256, 2) void conv_out_mfma(
    const u16* __restrict__ xin, const u16* __restrict__ Wt,
    const float* __restrict__ bias, float* __restrict__ out)
{
  __shared__ __align__(16) u16 xT[324 * 64];
  __shared__ __align__(16) u16 Bb[2 * 4096];
  conv_body<false, false>(xin, Wt, bias, out, blockIdx.x, xT, Bb, threadIdx.x);
}

// ---------------------------------------------------------------------------
// V transpose: vh [bh][s][2048] -> vt [bh][d][256]  (unchanged, verified)
// ---------------------------------------------------------------------------
__global__ __launch_bounds__(256) void transpose_v(
    const u16* __restrict__ vh, u16* __restrict__ vt)
{
  __shared__ u16 tile[64][72];
  const int tid = threadIdx.x;
  const int dt = blockIdx.x, st = blockIdx.y, bh = blockIdx.z;
  {
    int r = tid >> 2, c4 = tid & 3;
    const u16* src = vh + ((size_t)(bh*256 + st*64 + r))*2048 + dt*64 + c4*16;
    uint4 v0 = *(const uint4*)src;
    uint4 v1 = *(const uint4*)(src + 8);
    *(uint4*)&tile[r][c4*16]     = v0;
    *(uint4*)&tile[r][c4*16 + 8] = v1;
  }
  __syncthreads();
  {
    int dr = tid >> 2, s4 = tid & 3;
    u16 tmp[16];
    #pragma unroll
    for (int i = 0; i < 16; ++i) tmp[i] = tile[s4*16 + i][dr];
    u16* dstp = vt + ((size_t)(bh*2048 + dt*64 + dr))*256 + st*64 + s4*16;
    *(uint4*)dstp       = *(uint4*)&tmp[0];
    *(uint4*)(dstp + 8) = *(uint4*)&tmp[8];
  }
}

// ---------------------------------------------------------------------------
// Attention v3 (unchanged from R4, validated)
// ---------------------------------------------------------------------------
__global__ __launch_bounds__(512, 2) void attn_kernel(
    const u16* __restrict__ qh, const u16* __restrict__ kh,
    const u16* __restrict__ vt, u16* __restrict__ obuf)
{
  const float SCALE = 0.022097086912079608f;   // 1/sqrt(2048)
  __shared__ __align__(16) u16 Qs[16*2048];    // 64 KB; reused as V buf 0
  __shared__ __align__(16) u16 Kb[2][16384];   // 2 x 32 KB; reused as V buf 1
  __shared__ __align__(16) u16 P[16*256];      // 8 KB
  __shared__ float redA[8][16];
  __shared__ float redB[8][16];

  const int tid = threadIdx.x;
  const int w = tid >> 6, lane = tid & 63, lr = lane & 15, lg = lane >> 4;

  const int id = blockIdx.x;
  const int xcd = id & 7, j = id >> 3;
  const int bh = xcd + 8*(j & 1), qt = j >> 1;
  const int q0 = qt * 16, b = bh >> 3, h = bh & 7;

  const u16* Qg = qh + ((size_t)(bh*256 + q0))*2048;
  const u16* Kg = kh + (size_t)bh * 256 * 2048;
  const u16* Vg = vt + (size_t)bh * 2048 * 256;

  const int spK = (lane & 7) ^ ((lane >> 3) & 7);
  #define STAGE_K(c, buf)                                                   \
    _Pragma("unroll")                                                       \
    for (int r_ = 0; r_ < 4; ++r_)                                          \
      cp16_async(Kg + (size_t)(w*32 + r_*8 + (lane>>3))*2048 + (c)*64 + spK*8, \
                 (buf) + w*2048 + r_*512);

  #define STAGE_V(c, buf)                                                   \
    _Pragma("unroll")                                                       \
    for (int r_ = 0; r_ < 8; ++r_){                                         \
      int rl_ = w*16 + r_*2 + (lane>>5);                                    \
      int sp_ = (lane & 31) ^ (rl_ & 7);                                    \
      cp16_async(Vg + (size_t)((c)*128 + rl_)*256 + sp_*8,                  \
                 (buf) + w*4096 + r_*512);                                  \
    }

  #pragma unroll
  for (int r = 0; r < 8; ++r){
    int t = r*64 + lane;
    int row = w*2 + (t >> 8);
    int dp = t & 255;
    int sp = (dp & ~7) | ((dp & 7) ^ (row & 7));
    cp16_async(Qg + (size_t)row*2048 + sp*8, Qs + w*4096 + r*512);
  }
  STAGE_K(0, Kb[0]);
  __syncthreads();

  const f32x4 zero4 = {0.f, 0.f, 0.f, 0.f};
  f32x4 sacc[2] = {zero4, zero4};
  #pragma unroll 1
  for (int c = 0; c < 32; ++c){
    if (c < 31) STAGE_K(c+1, Kb[(c+1)&1]);
    const u16* kb = Kb[c&1];
    #pragma unroll
    for (int d2 = 0; d2 < 2; ++d2){
      unsigned aoff = (((unsigned)lr << 12) + (unsigned)(c*128 + d2*64 + lg*16))
                      ^ (unsigned)((lr & 7) << 4);
      s16x8 a = *(const s16x8*)((const char*)Qs + aoff);
      #pragma unroll
      for (int n = 0; n < 2; ++n){
        int row = w*32 + n*16 + lr;
        const u16* kp = kb + row*64 + (((d2*4 + lg) ^ (row & 7)) << 3);
        s16x8 bk = *(const s16x8*)kp;
        sacc[n] = __builtin_amdgcn_mfma_f32_16x16x32_bf16(a, bk, sacc[n], 0,0,0);
      }
    }
    __syncthreads();
  }

  float mx[4];
  #pragma unroll
  for (int r = 0; r < 4; ++r){
    float vv = fmaxf(sacc[0][r], sacc[1][r]);
    #pragma unroll
    for (int off = 1; off < 16; off <<= 1) vv = fmaxf(vv, __shfl_xor(vv, off));
    mx[r] = vv;
  }
  if (lr == 0){
    #pragma unroll
    for (int r = 0; r < 4; ++r) redA[w][lg*4 + r] = mx[r];
  }
  __syncthreads();
  #pragma unroll
  for (int r = 0; r < 4; ++r){
    int row = lg*4 + r;
    float vv = redA[0][row];
    #pragma unroll
    for (int ww = 1; ww < 8; ++ww) vv = fmaxf(vv, redA[ww][row]);
    mx[r] = vv;
  }

  const int kbase = w * 32;
  float sm[4] = {0.f, 0.f, 0.f, 0.f};
  #pragma unroll
  for (int n = 0; n < 2; ++n)
    #pragma unroll
    for (int r = 0; r < 4; ++r){
      float pv = __expf((sacc[n][r] - mx[r]) * SCALE);
      sm[r] += pv;
      int row = lg*4 + r;
      int col = kbase + n*16 + lr;
      unsigned off = (((unsigned)row << 9) + ((unsigned)col << 1))
                     ^ (unsigned)((row & 7) << 4);
      *(u16*)((char*)P + off) = f2bf(pv);
    }
  #pragma unroll
  for (int r = 0; r < 4; ++r){
    float vv = sm[r];
    #pragma unroll
    for (int off = 1; off < 16; off <<= 1) vv += __shfl_xor(vv, off);
    sm[r] = vv;
  }
  if (lr == 0){
    #pragma unroll
    for (int r = 0; r < 4; ++r) redB[w][lg*4 + r] = sm[r];
  }
  __syncthreads();
  float rs[4];
  #pragma unroll
  for (int r = 0; r < 4; ++r){
    int row = lg*4 + r;
    float s = redB[0][row];
    #pragma unroll
    for (int ww = 1; ww < 8; ++ww) s += redB[ww][row];
    rs[r] = 1.0f / s;
  }

  u16* Vb0 = Qs;
  u16* Vb1 = &Kb[0][0];
  STAGE_V(0, Vb0);
  __syncthreads();
  #pragma unroll 1
  for (int c = 0; c < 16; ++c){
    if (c < 15){
      u16* nbuf = ((c+1) & 1) ? Vb1 : Vb0;
      STAGE_V(c+1, nbuf);
    }
    const u16* vb = (c & 1) ? Vb1 : Vb0;
    f32x4 oacc = zero4;
    #pragma unroll
    for (int kt = 0; kt < 8; ++kt){
      unsigned poff = (((unsigned)lr << 9) + (unsigned)(kt*64 + lg*16))
                      ^ (unsigned)((lr & 7) << 4);
      s16x8 pa = *(const s16x8*)((const char*)P + poff);
      int row = w*16 + lr;
      const u16* vp = vb + row*256 + (((kt*4 + lg) ^ (row & 7)) << 3);
      s16x8 bv = *(const s16x8*)vp;
      oacc = __builtin_amdgcn_mfma_f32_16x16x32_bf16(pa, bv, oacc, 0,0,0);
    }
    #pragma unroll
    for (int r = 0; r < 4; ++r){
      float o = oacc[r] * rs[r];
      int qrow = q0 + lg*4 + r;
      int d = c*128 + w*16 + lr;
      int frame = b*256 + qrow;
      int cdim = h*8 + (d >> 8);
      obuf[((size_t)(frame*64 + cdim))*256 + (d & 255)] = f2bf(o);
    }
    __syncthreads();
  }
  #undef STAGE_K
  #undef STAGE_V
}

// ---------------------------------------------------------------------------
extern "C" void kernel_launch(void* const* d_in, const int* in_sizes, int n_in,
                              void* d_out, int out_size, void* d_ws, size_t ws_size,
                              hipStream_t stream)
{
  const float* q  = (const float*)d_in[0];
  const float* k  = (const float*)d_in[1];
  const float* v  = (const float*)d_in[2];
  const float* Wq = (const float*)d_in[3];
  const float* bq = (const float*)d_in[4];
  const float* Wk = (const float*)d_in[5];
  const float* bk = (const float*)d_in[6];
  const float* Wv = (const float*)d_in[7];
  const float* bv = (const float*)d_in[8];
  const float* Wo = (const float*)d_in[9];
  const float* bo = (const float*)d_in[10];
  float* out = (float*)d_out;

  // Workspace (64 MB): qh[0,16M) kh[16,32M) vh[32,48M) vt[48,64M)
  char* ws = (char*)d_ws;
  u16* qh = (u16*)(ws);
  u16* kh = (u16*)(ws + (size_t)16*1024*1024);
  u16* vh = (u16*)(ws + (size_t)32*1024*1024);
  u16* vt = (u16*)(ws + (size_t)48*1024*1024);
  u16* obuf = vh;          // attn output frames (vh dead after transpose_v)
  u16* Wt3  = vt;          // 3 weight packs; dead before transpose_v clobbers
  u16* WtO  = qh;          // qh dead after attn

  prep_w3<<<dim3(144, 3), dim3(256), 0, stream>>>(Wq, Wk, Wv, Wt3);
  conv3_mfma<<<dim3(1536), dim3(256), 0, stream>>>(q, k, v, Wt3, bq, bk, bv,
                                                   qh, kh, vh);
  transpose_v<<<dim3(32, 4, 16), dim3(256), 0, stream>>>(vh, vt);
  attn_kernel<<<dim3(256), dim3(512), 0, stream>>>(qh, kh, vt, obuf);
  prep_w<<<dim3(144), dim3(256), 0, stream>>>(Wo, WtO);
  conv_out_mfma<<<dim3(512), dim3(256), 0, stream>>>(obuf, WtO, bo, out);
}